// Round 5
// baseline (758.073 us; speedup 1.0000x reference)
//
#include <hip/hip_runtime.h>

// Attention_5823975653530: out = softmax(tanh(Q K^T) + mask) @ V, also returns weights.
// B=4,H=16,T1=T2=1024,DK=DV=64. All f32 in/out.
//
// Strategy: per-wave 16 q-rows, swapped QK^T (S^T = mfma(K,Q)) so that the S^T
// C-fragment layout (col=lane&15=q, row=c=4*(lane>>4)+i) is IDENTICAL to the
// A-fragment layout of mfma_f32_16x16x16_f16 used for PV -> P stays in 128
// VGPRs (f16x4[64]), no LDS, no barriers, no shuffles except the 2-step
// row-sum reduction. Weights written as coalesced dwordx4 (w = p * 1/Z).

typedef _Float16 f16;
typedef __attribute__((ext_vector_type(2))) _Float16 f16x2;
typedef __attribute__((ext_vector_type(4))) _Float16 f16x4;
typedef __attribute__((ext_vector_type(8))) _Float16 f16x8;
typedef __attribute__((ext_vector_type(2))) __fp16  fp16x2;  // cvt_pkrtz native type
typedef __attribute__((ext_vector_type(4))) float f32x4;

#define LOG2E 1.44269504088896340736f

union U8 { f16x8 v; f16x2 h[4]; };
union U4 { f16x4 v; f16x2 h[2]; };

// cvt_pkrtz returns __fp16x2; bit-cast to _Float16x2 (MFMA operand base type).
static __device__ __forceinline__ f16x2 pk(float a, float b) {
  union { fp16x2 src; f16x2 dst; } u;
  u.src = __builtin_amdgcn_cvt_pkrtz(a, b);
  return u.dst;
}

__global__ __launch_bounds__(256, 2) void attn_fused(
    const float* __restrict__ Q, const float* __restrict__ K,
    const float* __restrict__ V, const float* __restrict__ M,
    float* __restrict__ Out, float* __restrict__ W)
{
  const int bh   = blockIdx.x >> 4;   // b*16+h, 0..63
  const int qt   = blockIdx.x & 15;   // q-tile of 64 rows
  const int b    = bh >> 4;           // 0..3
  const int lane = threadIdx.x & 63;
  const int wv   = threadIdx.x >> 6;  // wave 0..3
  const int qv   = lane & 15;         // q within 16 (pass1 C-col / pass2 A-row)
  const int g    = lane >> 4;         // lane group 0..3
  const int qbase = qt * 64 + wv * 16;

  // ---- Q B-fragments for S^T = K * Q : B[k=d][col=q], lane reads Q[qbase+qv][g*8 + j] ----
  const float* qp = Q + ((size_t)(bh * 1024 + qbase + qv)) * 64 + g * 8;
  f16x8 bq[2];
  #pragma unroll
  for (int ks = 0; ks < 2; ++ks) {
    f32x4 a = *(const f32x4*)(qp + ks * 32);
    f32x4 c = *(const f32x4*)(qp + ks * 32 + 4);
    U8 u;
    u.h[0] = pk(a[0], a[1]);
    u.h[1] = pk(a[2], a[3]);
    u.h[2] = pk(c[0], c[1]);
    u.h[3] = pk(c[2], c[3]);
    bq[ks] = u.v;
  }

  // K A-fragment base: A[row=c][k=d], lane reads K[fc*16+qv][g*8 + j]
  const float* kp = K + ((size_t)(b * 1024 + qv)) * 64 + g * 8;
  // mask: lane holds (q=qv, c=fc*16+4g+i) -> one dwordx4 per tile
  const float* mp = M + (size_t)(qbase + qv) * 1024 + g * 4;

  f16x4 P[64];          // resident probabilities (unnormalized e^{tanh+mask}), f16
  float rsum = 0.0f;

  #pragma unroll
  for (int fc = 0; fc < 64; ++fc) {
    const float* kf = kp + fc * 1024;  // 16 rows of K per tile
    f16x8 ak[2];
    #pragma unroll
    for (int ks = 0; ks < 2; ++ks) {
      f32x4 a = *(const f32x4*)(kf + ks * 32);
      f32x4 c = *(const f32x4*)(kf + ks * 32 + 4);
      U8 u;
      u.h[0] = pk(a[0], a[1]);
      u.h[1] = pk(a[2], a[3]);
      u.h[2] = pk(c[0], c[1]);
      u.h[3] = pk(c[2], c[3]);
      ak[ks] = u.v;
    }
    f32x4 acc = {0.f, 0.f, 0.f, 0.f};
    acc = __builtin_amdgcn_mfma_f32_16x16x32_f16(ak[0], bq[0], acc, 0, 0, 0);
    acc = __builtin_amdgcn_mfma_f32_16x16x32_f16(ak[1], bq[1], acc, 0, 0, 0);

    f32x4 m4 = *(const f32x4*)(mp + fc * 16);

    // p = exp(tanh(x) + m); tanh(x) = 1 - 2/(e^{2x}+1); all via exp2/rcp,
    // saturates correctly for |x| large (inf/0 -> r=0/1), no clamp needed.
    float p[4];
    #pragma unroll
    for (int i = 0; i < 4; ++i) {
      float x = acc[i];
      float t = __builtin_amdgcn_exp2f(x * (2.0f * LOG2E));        // e^{2x}
      float r = __builtin_amdgcn_rcpf(t + 1.0f);                   // 1/(e^{2x}+1)
      // (1 - 2r + m)*log2e = fma(m, L, fma(r, -2L, L))
      p[i] = __builtin_amdgcn_exp2f(
                 fmaf(m4[i], LOG2E, fmaf(r, -2.0f * LOG2E, LOG2E)));
    }
    rsum += (p[0] + p[1]) + (p[2] + p[3]);
    U4 u;
    u.h[0] = pk(p[0], p[1]);
    u.h[1] = pk(p[2], p[3]);
    P[fc] = u.v;
  }

  // row sums: lanes l, l^16, l^32, l^48 share the same q=lane&15
  rsum += __shfl_xor(rsum, 16);
  rsum += __shfl_xor(rsum, 32);
  const float rz = 1.0f / rsum;      // 1/Z for q = qv
  // 1/Z for q = g*4+i (needed for the out store whose rows are 4g+i)
  float rzq[4];
  #pragma unroll
  for (int i = 0; i < 4; ++i) rzq[i] = __shfl(rz, g * 4 + i);

  // ---- pass 2: weights write + PV via mfma_f32_16x16x16_f16 ----
  // V B-frag: B[k=c][col=n], lane reads V[fc*16 + g*4 + j][nb*16 + qv]
  const float* vp = V + (size_t)b * 65536 + g * 256 + qv;
  float* wl = W + ((size_t)(bh * 1024 + qbase + qv)) * 1024 + g * 4;
  f32x4 oacc[4];
  #pragma unroll
  for (int nb = 0; nb < 4; ++nb) oacc[nb] = f32x4{0.f, 0.f, 0.f, 0.f};

  #pragma unroll
  for (int fc = 0; fc < 64; ++fc) {
    U4 pu; pu.v = P[fc];
    // weights: w = p * 1/Z, 16B contiguous per lane, full 64B segments per row
    f32x4 w4;
    w4[0] = (float)pu.h[0][0] * rz;
    w4[1] = (float)pu.h[0][1] * rz;
    w4[2] = (float)pu.h[1][0] * rz;
    w4[3] = (float)pu.h[1][1] * rz;
    *(f32x4*)(wl + fc * 16) = w4;

    const float* vf = vp + fc * 1024;
    #pragma unroll
    for (int nb = 0; nb < 4; ++nb) {
      U4 bu;
      bu.h[0] = pk(vf[nb * 16],       vf[nb * 16 + 64]);
      bu.h[1] = pk(vf[nb * 16 + 128], vf[nb * 16 + 192]);
      oacc[nb] = __builtin_amdgcn_mfma_f32_16x16x16f16(P[fc], bu.v, oacc[nb], 0, 0, 0);
    }
  }

  // out store: rows q = g*4+i, cols n = nb*16+qv; scale by 1/Z (unnormalized PV)
  float* ol = Out + ((size_t)(bh * 1024 + qbase)) * 64 + qv;
  #pragma unroll
  for (int nb = 0; nb < 4; ++nb) {
    #pragma unroll
    for (int i = 0; i < 4; ++i) {
      ol[(size_t)(g * 4 + i) * 64 + nb * 16] = oacc[nb][i] * rzq[i];
    }
  }
}

extern "C" void kernel_launch(void* const* d_in, const int* in_sizes, int n_in,
                              void* d_out, int out_size, void* d_ws, size_t ws_size,
                              hipStream_t stream) {
  const float* Q = (const float*)d_in[0];
  const float* K = (const float*)d_in[1];
  const float* V = (const float*)d_in[2];
  const float* M = (const float*)d_in[3];
  float* Out = (float*)d_out;
  float* W   = Out + (size_t)4 * 16 * 1024 * 64;   // out first, then weights
  hipLaunchKernelGGL(attn_fused, dim3(1024), dim3(256), 0, stream,
                     Q, K, V, M, Out, W);
}

// Round 6
// 570.223 us; speedup vs baseline: 1.3294x; 1.3294x over previous
//
#include <hip/hip_runtime.h>

// Attention_5823975653530: out = softmax(tanh(Q K^T) + mask) @ V, also returns weights.
// B=4,H=16,T1=T2=1024,DK=DV=64. All f32 in/out.
//
// v2: NO P[64] residency (v1 spilled it to scratch: VGPR=84 < 128 needed,
// occupancy 26%, all pipes idle, 513us). PV is linear in p -> fold PV into
// phase 1 with unnormalized p, scale by 1/Z at the end. Phase 2 RECOMPUTES
// QK^T+tanh+exp per tile (K is L2-resident; uses idle VALU/MFMA pipes) and
// streams W = p * 1/Z. Zero inter-phase state except rz -> ~70 VGPR,
// launch_bounds(256,4) = 16 waves/CU.
//
// Layouts (verified r0-r4): S^T = mfma_f32_16x16x32_f16(A=K,B=Q): C col=lane&15=q,
// row=4*(lane>>4)+i=c. This C layout == A-frag layout of mfma_f32_16x16x16f16
// (row=lane&15, k=4*(lane>>4)+j) -> p feeds PV with zero cross-lane movement.

typedef _Float16 f16;
typedef __attribute__((ext_vector_type(2))) _Float16 f16x2;
typedef __attribute__((ext_vector_type(4))) _Float16 f16x4;
typedef __attribute__((ext_vector_type(8))) _Float16 f16x8;
typedef __attribute__((ext_vector_type(2))) __fp16  fp16x2;  // cvt_pkrtz native type
typedef __attribute__((ext_vector_type(4))) float f32x4;

#define LOG2E 1.44269504088896340736f

union U8 { f16x8 v; f16x2 h[4]; };
union U4 { f16x4 v; f16x2 h[2]; };

// cvt_pkrtz returns __fp16x2; bit-cast to _Float16x2 (MFMA operand base type).
static __device__ __forceinline__ f16x2 pk(float a, float b) {
  union { fp16x2 src; f16x2 dst; } u;
  u.src = __builtin_amdgcn_cvt_pkrtz(a, b);
  return u.dst;
}

// p[i] = exp(tanh(acc[i]) + m4[i]); tanh via 1 - 2/(e^{2x}+1); exp via exp2.
// Saturates correctly for |x| large (rcp -> 0/1), no clamps needed.
static __device__ __forceinline__ void tanh_exp4(const f32x4& acc, const f32x4& m4,
                                                 float p[4]) {
  #pragma unroll
  for (int i = 0; i < 4; ++i) {
    float x = acc[i];
    float t = __builtin_amdgcn_exp2f(x * (2.0f * LOG2E));      // e^{2x}
    float r = __builtin_amdgcn_rcpf(t + 1.0f);                 // 1/(e^{2x}+1)
    p[i] = __builtin_amdgcn_exp2f(
               fmaf(m4[i], LOG2E, fmaf(r, -2.0f * LOG2E, LOG2E)));
  }
}

__global__ __launch_bounds__(256, 4) void attn_fused(
    const float* __restrict__ Q, const float* __restrict__ K,
    const float* __restrict__ V, const float* __restrict__ M,
    float* __restrict__ Out, float* __restrict__ W)
{
  const int bh   = blockIdx.x >> 4;   // b*16+h, 0..63
  const int qt   = blockIdx.x & 15;   // q-tile of 64 rows
  const int b    = bh >> 4;           // 0..3
  const int lane = threadIdx.x & 63;
  const int wv   = threadIdx.x >> 6;  // wave 0..3
  const int qv   = lane & 15;         // q within 16 (pass1 C-col / PV A-row)
  const int g    = lane >> 4;         // lane group 0..3
  const int qbase = qt * 64 + wv * 16;

  // ---- Q B-fragments for S^T = K * Q : B[k=d][col=q], lane reads Q[qbase+qv][g*8 + j] ----
  const float* qp = Q + ((size_t)(bh * 1024 + qbase + qv)) * 64 + g * 8;
  f16x8 bq[2];
  #pragma unroll
  for (int ks = 0; ks < 2; ++ks) {
    f32x4 a = *(const f32x4*)(qp + ks * 32);
    f32x4 c = *(const f32x4*)(qp + ks * 32 + 4);
    U8 u;
    u.h[0] = pk(a[0], a[1]);
    u.h[1] = pk(a[2], a[3]);
    u.h[2] = pk(c[0], c[1]);
    u.h[3] = pk(c[2], c[3]);
    bq[ks] = u.v;
  }

  // K A-fragment base: A[row=c][k=d], lane reads K[fc*16+qv][g*8 + j]
  const float* kp = K + ((size_t)(b * 1024 + qv)) * 64 + g * 8;
  // mask: lane holds (q=qv, c=fc*16+4g+i) -> one dwordx4 per tile
  const float* mp = M + (size_t)(qbase + qv) * 1024 + g * 4;
  // V B-frag: B[k=c][col=n], lane reads V[fc*16 + g*4 + j][nb*16 + qv]
  const float* vp = V + (size_t)b * 65536 + g * 256 + qv;

  float rsum = 0.0f;
  f32x4 oacc[4];
  #pragma unroll
  for (int nb = 0; nb < 4; ++nb) oacc[nb] = f32x4{0.f, 0.f, 0.f, 0.f};

  // ===== phase 1: QK^T -> p -> {rsum, PV(unnormalized)} ; no W, no P storage =====
  #pragma unroll 2
  for (int fc = 0; fc < 64; ++fc) {
    const float* kf = kp + fc * 1024;  // 16 rows of K per tile
    f16x8 ak[2];
    #pragma unroll
    for (int ks = 0; ks < 2; ++ks) {
      f32x4 a = *(const f32x4*)(kf + ks * 32);
      f32x4 c = *(const f32x4*)(kf + ks * 32 + 4);
      U8 u;
      u.h[0] = pk(a[0], a[1]);
      u.h[1] = pk(a[2], a[3]);
      u.h[2] = pk(c[0], c[1]);
      u.h[3] = pk(c[2], c[3]);
      ak[ks] = u.v;
    }
    f32x4 acc = {0.f, 0.f, 0.f, 0.f};
    acc = __builtin_amdgcn_mfma_f32_16x16x32_f16(ak[0], bq[0], acc, 0, 0, 0);
    acc = __builtin_amdgcn_mfma_f32_16x16x32_f16(ak[1], bq[1], acc, 0, 0, 0);

    f32x4 m4 = *(const f32x4*)(mp + fc * 16);
    float p[4];
    tanh_exp4(acc, m4, p);
    rsum += (p[0] + p[1]) + (p[2] + p[3]);

    U4 pu;
    pu.h[0] = pk(p[0], p[1]);
    pu.h[1] = pk(p[2], p[3]);

    const float* vf = vp + fc * 1024;
    #pragma unroll
    for (int nb = 0; nb < 4; ++nb) {
      U4 bu;
      bu.h[0] = pk(vf[nb * 16],       vf[nb * 16 + 64]);
      bu.h[1] = pk(vf[nb * 16 + 128], vf[nb * 16 + 192]);
      oacc[nb] = __builtin_amdgcn_mfma_f32_16x16x16f16(pu.v, bu.v, oacc[nb], 0, 0, 0);
    }
  }

  // row sums: lanes l, l^16, l^32, l^48 share the same q=lane&15
  rsum += __shfl_xor(rsum, 16);
  rsum += __shfl_xor(rsum, 32);
  const float rz = 1.0f / rsum;      // 1/Z for q = qv
  // 1/Z for q = g*4+i (out-store rows are 4g+i)
  float rzq[4];
  #pragma unroll
  for (int i = 0; i < 4; ++i) rzq[i] = __shfl(rz, g * 4 + i);

  // out store: rows q = g*4+i, cols n = nb*16+qv; scale by 1/Z
  float* ol = Out + ((size_t)(bh * 1024 + qbase)) * 64 + qv;
  #pragma unroll
  for (int nb = 0; nb < 4; ++nb) {
    #pragma unroll
    for (int i = 0; i < 4; ++i) {
      ol[(size_t)(g * 4 + i) * 64 + nb * 16] = oacc[nb][i] * rzq[i];
    }
  }

  // ===== phase 2: recompute QK^T -> p, stream W = p * 1/Z (coalesced dwordx4) =====
  float* wl = W + ((size_t)(bh * 1024 + qbase + qv)) * 1024 + g * 4;
  #pragma unroll 2
  for (int fc = 0; fc < 64; ++fc) {
    const float* kf = kp + fc * 1024;
    f16x8 ak[2];
    #pragma unroll
    for (int ks = 0; ks < 2; ++ks) {
      f32x4 a = *(const f32x4*)(kf + ks * 32);
      f32x4 c = *(const f32x4*)(kf + ks * 32 + 4);
      U8 u;
      u.h[0] = pk(a[0], a[1]);
      u.h[1] = pk(a[2], a[3]);
      u.h[2] = pk(c[0], c[1]);
      u.h[3] = pk(c[2], c[3]);
      ak[ks] = u.v;
    }
    f32x4 acc = {0.f, 0.f, 0.f, 0.f};
    acc = __builtin_amdgcn_mfma_f32_16x16x32_f16(ak[0], bq[0], acc, 0, 0, 0);
    acc = __builtin_amdgcn_mfma_f32_16x16x32_f16(ak[1], bq[1], acc, 0, 0, 0);

    f32x4 m4 = *(const f32x4*)(mp + fc * 16);
    float p[4];
    tanh_exp4(acc, m4, p);

    f32x4 w4;
    w4[0] = p[0] * rz;
    w4[1] = p[1] * rz;
    w4[2] = p[2] * rz;
    w4[3] = p[3] * rz;
    *(f32x4*)(wl + fc * 16) = w4;
  }
}

extern "C" void kernel_launch(void* const* d_in, const int* in_sizes, int n_in,
                              void* d_out, int out_size, void* d_ws, size_t ws_size,
                              hipStream_t stream) {
  const float* Q = (const float*)d_in[0];
  const float* K = (const float*)d_in[1];
  const float* V = (const float*)d_in[2];
  const float* M = (const float*)d_in[3];
  float* Out = (float*)d_out;
  float* W   = Out + (size_t)4 * 16 * 1024 * 64;   // out first, then weights
  hipLaunchKernelGGL(attn_fused, dim3(1024), dim3(256), 0, stream,
                     Q, K, V, M, Out, W);
}

// Round 9
// 374.691 us; speedup vs baseline: 2.0232x; 1.5218x over previous
//
#include <hip/hip_runtime.h>

// Attention_5823975653530: out = softmax(tanh(Q K^T) + mask) @ V, + weights.
// B=4,H=16,T1=T2=1024,DK=DV=64. All f32 in/out.
//
// v3: r6 was latency/TA-scatter-bound (344us, all pipes idle): 21 vmem insts
// per wave per tile, each scattering 64 lanes over 16 x 64B lines, plus 4x
// redundant K/V load+f16-convert across waves. Fix: one-time `prep` kernel
// repacks K,V (f16, exact MFMA fragment order) and M (f32, fragment order)
// into d_ws so every hot-loop load is base + lane*width (fully coalesced).
// No LDS, no barriers, no in-loop K/V converts.
//
// Layouts (verified pass r5/r6):
//   S^T = mfma_f32_16x16x32_f16(A=K,B=Q): C col=lane&15=q, row=4*(lane>>4)+i=c
//   C layout == A-frag of mfma_f32_16x16x16f16 -> p feeds PV in-register.
//   Kp[b][fc][ks][l][j] = K[b][fc*16+(l&15)][(l>>4)*8+ks*32+j]   (f16, j=0..7)
//   Vp[b][fc][nb][l][j] = V[b][fc*16+(l>>4)*4+j][nb*16+(l&15)]   (f16, j=0..3)
//   Mp[q16][fc][l][i]   = M[q16*16+(l&15)][fc*16+(l>>4)*4+i]     (f32, i=0..3)

typedef _Float16 f16;
typedef __attribute__((ext_vector_type(2))) _Float16 f16x2;
typedef __attribute__((ext_vector_type(4))) _Float16 f16x4;
typedef __attribute__((ext_vector_type(8))) _Float16 f16x8;
typedef __attribute__((ext_vector_type(2))) __fp16  fp16x2;  // cvt_pkrtz native type
typedef __attribute__((ext_vector_type(4))) float f32x4;

#define LOG2E 1.44269504088896340736f

union U8 { f16x8 v; f16x2 h[4]; };
union U4 { f16x4 v; f16x2 h[2]; };

static __device__ __forceinline__ f16x2 pk(float a, float b) {
  union { fp16x2 src; f16x2 dst; } u;
  u.src = __builtin_amdgcn_cvt_pkrtz(a, b);
  return u.dst;
}

// p[i] = exp(tanh(acc[i]) + m4[i]); tanh via 1 - 2/(e^{2x}+1); exp via exp2.
static __device__ __forceinline__ void tanh_exp4(const f32x4& acc, const f32x4& m4,
                                                 float p[4]) {
  #pragma unroll
  for (int i = 0; i < 4; ++i) {
    float x = acc[i];
    float t = __builtin_amdgcn_exp2f(x * (2.0f * LOG2E));      // e^{2x}
    float r = __builtin_amdgcn_rcpf(t + 1.0f);                 // 1/(e^{2x}+1)
    p[i] = __builtin_amdgcn_exp2f(
               fmaf(m4[i], LOG2E, fmaf(r, -2.0f * LOG2E, LOG2E)));
  }
}

// ---------------- prep: repack K,V->f16 fragment order, M->f32 fragment order --
// units: Kp 32768 (16B each) | Vp 65536 (8B) | Mp 262144 (16B); total 360448.
__global__ __launch_bounds__(256) void prep(
    const float* __restrict__ K, const float* __restrict__ V,
    const float* __restrict__ M,
    f16* __restrict__ Kp, f16* __restrict__ Vp, float* __restrict__ Mp)
{
  int idx = blockIdx.x * 256 + threadIdx.x;
  if (idx < 32768) {                       // Kp[b][fc][ks][l][0..7]
    int l = idx & 63, ks = (idx >> 6) & 1, fc = (idx >> 7) & 63, b = idx >> 13;
    const float* s = K + ((size_t)b * 1024 + fc * 16 + (l & 15)) * 64
                       + (l >> 4) * 8 + ks * 32;
    f32x4 x = *(const f32x4*)s;
    f32x4 y = *(const f32x4*)(s + 4);
    U8 u;
    u.h[0] = pk(x[0], x[1]); u.h[1] = pk(x[2], x[3]);
    u.h[2] = pk(y[0], y[1]); u.h[3] = pk(y[2], y[3]);
    *(f16x8*)(Kp + (size_t)idx * 8) = u.v;
  } else if (idx < 98304) {                // Vp[b][fc][nb][l][0..3]
    int t = idx - 32768;
    int l = t & 63, nb = (t >> 6) & 3, fc = (t >> 8) & 63, b = t >> 14;
    const float* s = V + ((size_t)b * 1024 + fc * 16 + (l >> 4) * 4) * 64
                       + nb * 16 + (l & 15);
    U4 u;
    u.h[0] = pk(s[0],   s[64]);
    u.h[1] = pk(s[128], s[192]);
    *(f16x4*)(Vp + (size_t)t * 4) = u.v;
  } else if (idx < 360448) {               // Mp[q16][fc][l][0..3]
    int t = idx - 98304;
    int l = t & 63, fc = (t >> 6) & 63, q16 = t >> 12;
    const float* s = M + ((size_t)q16 * 16 + (l & 15)) * 1024
                       + fc * 16 + (l >> 4) * 4;
    *(f32x4*)(Mp + (size_t)t * 4) = *(const f32x4*)s;
  }
}

// ---------------- main: all hot-loop loads are base + lane*width ---------------
__global__ __launch_bounds__(256, 4) void attn_main(
    const float* __restrict__ Q, const f16* __restrict__ Kp,
    const f16* __restrict__ Vp, const float* __restrict__ Mp,
    float* __restrict__ Out, float* __restrict__ W)
{
  const int bh   = blockIdx.x >> 4;   // b*16+h
  const int qt   = blockIdx.x & 15;
  const int b    = bh >> 4;
  const int lane = threadIdx.x & 63;
  const int wv   = threadIdx.x >> 6;
  const int qv   = lane & 15;
  const int g    = lane >> 4;
  const int qbase = qt * 64 + wv * 16;

  // Q B-frags (one-time, from Q): lane reads Q[qbase+qv][g*8 + ks*32 + j]
  const float* qp = Q + ((size_t)(bh * 1024 + qbase + qv)) * 64 + g * 8;
  f16x8 bq[2];
  #pragma unroll
  for (int ks = 0; ks < 2; ++ks) {
    f32x4 a = *(const f32x4*)(qp + ks * 32);
    f32x4 c = *(const f32x4*)(qp + ks * 32 + 4);
    U8 u;
    u.h[0] = pk(a[0], a[1]); u.h[1] = pk(a[2], a[3]);
    u.h[2] = pk(c[0], c[1]); u.h[3] = pk(c[2], c[3]);
    bq[ks] = u.v;
  }

  const f16*   kpB = Kp + (size_t)b * 65536 + lane * 8;          // + fc*1024 + ks*512
  const f16*   vpB = Vp + (size_t)b * 65536 + lane * 4;          // + fc*1024 + nb*256
  const float* mpB = Mp + (size_t)(qt * 4 + wv) * 16384 + lane * 4;  // + fc*256

  float rsum = 0.0f;
  f32x4 oacc[4];
  #pragma unroll
  for (int nb = 0; nb < 4; ++nb) oacc[nb] = f32x4{0.f, 0.f, 0.f, 0.f};

  // ===== phase 1: QK^T -> p -> {rsum, PV(unnormalized)} =====
  #pragma unroll 2
  for (int fc = 0; fc < 64; ++fc) {
    f16x8 a0 = *(const f16x8*)(kpB + fc * 1024);
    f16x8 a1 = *(const f16x8*)(kpB + fc * 1024 + 512);
    f32x4 acc = {0.f, 0.f, 0.f, 0.f};
    acc = __builtin_amdgcn_mfma_f32_16x16x32_f16(a0, bq[0], acc, 0, 0, 0);
    acc = __builtin_amdgcn_mfma_f32_16x16x32_f16(a1, bq[1], acc, 0, 0, 0);

    f32x4 m4 = *(const f32x4*)(mpB + fc * 256);
    float p[4];
    tanh_exp4(acc, m4, p);
    rsum += (p[0] + p[1]) + (p[2] + p[3]);

    U4 pu;
    pu.h[0] = pk(p[0], p[1]);
    pu.h[1] = pk(p[2], p[3]);

    #pragma unroll
    for (int nb = 0; nb < 4; ++nb) {
      f16x4 bv = *(const f16x4*)(vpB + fc * 1024 + nb * 256);
      oacc[nb] = __builtin_amdgcn_mfma_f32_16x16x16f16(pu.v, bv, oacc[nb], 0, 0, 0);
    }
  }

  // row sums: lanes l, l^16, l^32, l^48 share the same q=lane&15
  rsum += __shfl_xor(rsum, 16);
  rsum += __shfl_xor(rsum, 32);
  const float rz = 1.0f / rsum;
  float rzq[4];
  #pragma unroll
  for (int i = 0; i < 4; ++i) rzq[i] = __shfl(rz, g * 4 + i);

  // out store: rows q = g*4+i, cols n = nb*16+qv
  float* ol = Out + ((size_t)(bh * 1024 + qbase)) * 64 + qv;
  #pragma unroll
  for (int nb = 0; nb < 4; ++nb) {
    #pragma unroll
    for (int i = 0; i < 4; ++i) {
      ol[(size_t)(g * 4 + i) * 64 + nb * 16] = oacc[nb][i] * rzq[i];
    }
  }

  // ===== phase 2: recompute p, stream W = p * 1/Z (coalesced dwordx4) =====
  float* wl = W + ((size_t)(bh * 1024 + qbase + qv)) * 1024 + g * 4;
  #pragma unroll 4
  for (int fc = 0; fc < 64; ++fc) {
    f16x8 a0 = *(const f16x8*)(kpB + fc * 1024);
    f16x8 a1 = *(const f16x8*)(kpB + fc * 1024 + 512);
    f32x4 acc = {0.f, 0.f, 0.f, 0.f};
    acc = __builtin_amdgcn_mfma_f32_16x16x32_f16(a0, bq[0], acc, 0, 0, 0);
    acc = __builtin_amdgcn_mfma_f32_16x16x32_f16(a1, bq[1], acc, 0, 0, 0);

    f32x4 m4 = *(const f32x4*)(mpB + fc * 256);
    float p[4];
    tanh_exp4(acc, m4, p);

    f32x4 w4;
    w4[0] = p[0] * rz; w4[1] = p[1] * rz;
    w4[2] = p[2] * rz; w4[3] = p[3] * rz;
    *(f32x4*)(wl + fc * 16) = w4;
  }
}

// ---------------- fallback (r6 kernel, known-pass) if ws too small -------------
__global__ __launch_bounds__(256, 4) void attn_fused(
    const float* __restrict__ Q, const float* __restrict__ K,
    const float* __restrict__ V, const float* __restrict__ M,
    float* __restrict__ Out, float* __restrict__ W)
{
  const int bh   = blockIdx.x >> 4;
  const int qt   = blockIdx.x & 15;
  const int b    = bh >> 4;
  const int lane = threadIdx.x & 63;
  const int wv   = threadIdx.x >> 6;
  const int qv   = lane & 15;
  const int g    = lane >> 4;
  const int qbase = qt * 64 + wv * 16;

  const float* qp = Q + ((size_t)(bh * 1024 + qbase + qv)) * 64 + g * 8;
  f16x8 bq[2];
  #pragma unroll
  for (int ks = 0; ks < 2; ++ks) {
    f32x4 a = *(const f32x4*)(qp + ks * 32);
    f32x4 c = *(const f32x4*)(qp + ks * 32 + 4);
    U8 u;
    u.h[0] = pk(a[0], a[1]); u.h[1] = pk(a[2], a[3]);
    u.h[2] = pk(c[0], c[1]); u.h[3] = pk(c[2], c[3]);
    bq[ks] = u.v;
  }
  const float* kp = K + ((size_t)(b * 1024 + qv)) * 64 + g * 8;
  const float* mp = M + (size_t)(qbase + qv) * 1024 + g * 4;
  const float* vp = V + (size_t)b * 65536 + g * 256 + qv;

  float rsum = 0.0f;
  f32x4 oacc[4];
  #pragma unroll
  for (int nb = 0; nb < 4; ++nb) oacc[nb] = f32x4{0.f, 0.f, 0.f, 0.f};

  #pragma unroll 2
  for (int fc = 0; fc < 64; ++fc) {
    const float* kf = kp + fc * 1024;
    f16x8 ak[2];
    #pragma unroll
    for (int ks = 0; ks < 2; ++ks) {
      f32x4 a = *(const f32x4*)(kf + ks * 32);
      f32x4 c = *(const f32x4*)(kf + ks * 32 + 4);
      U8 u;
      u.h[0] = pk(a[0], a[1]); u.h[1] = pk(a[2], a[3]);
      u.h[2] = pk(c[0], c[1]); u.h[3] = pk(c[2], c[3]);
      ak[ks] = u.v;
    }
    f32x4 acc = {0.f, 0.f, 0.f, 0.f};
    acc = __builtin_amdgcn_mfma_f32_16x16x32_f16(ak[0], bq[0], acc, 0, 0, 0);
    acc = __builtin_amdgcn_mfma_f32_16x16x32_f16(ak[1], bq[1], acc, 0, 0, 0);
    f32x4 m4 = *(const f32x4*)(mp + fc * 16);
    float p[4];
    tanh_exp4(acc, m4, p);
    rsum += (p[0] + p[1]) + (p[2] + p[3]);
    U4 pu;
    pu.h[0] = pk(p[0], p[1]);
    pu.h[1] = pk(p[2], p[3]);
    const float* vf = vp + fc * 1024;
    #pragma unroll
    for (int nb = 0; nb < 4; ++nb) {
      U4 bu;
      bu.h[0] = pk(vf[nb * 16],       vf[nb * 16 + 64]);
      bu.h[1] = pk(vf[nb * 16 + 128], vf[nb * 16 + 192]);
      oacc[nb] = __builtin_amdgcn_mfma_f32_16x16x16f16(pu.v, bu.v, oacc[nb], 0, 0, 0);
    }
  }
  rsum += __shfl_xor(rsum, 16);
  rsum += __shfl_xor(rsum, 32);
  const float rz = 1.0f / rsum;
  float rzq[4];
  #pragma unroll
  for (int i = 0; i < 4; ++i) rzq[i] = __shfl(rz, g * 4 + i);
  float* ol = Out + ((size_t)(bh * 1024 + qbase)) * 64 + qv;
  #pragma unroll
  for (int nb = 0; nb < 4; ++nb)
    #pragma unroll
    for (int i = 0; i < 4; ++i)
      ol[(size_t)(g * 4 + i) * 64 + nb * 16] = oacc[nb][i] * rzq[i];

  float* wl = W + ((size_t)(bh * 1024 + qbase + qv)) * 1024 + g * 4;
  #pragma unroll 2
  for (int fc = 0; fc < 64; ++fc) {
    const float* kf = kp + fc * 1024;
    f16x8 ak[2];
    #pragma unroll
    for (int ks = 0; ks < 2; ++ks) {
      f32x4 a = *(const f32x4*)(kf + ks * 32);
      f32x4 c = *(const f32x4*)(kf + ks * 32 + 4);
      U8 u;
      u.h[0] = pk(a[0], a[1]); u.h[1] = pk(a[2], a[3]);
      u.h[2] = pk(c[0], c[1]); u.h[3] = pk(c[2], c[3]);
      ak[ks] = u.v;
    }
    f32x4 acc = {0.f, 0.f, 0.f, 0.f};
    acc = __builtin_amdgcn_mfma_f32_16x16x32_f16(ak[0], bq[0], acc, 0, 0, 0);
    acc = __builtin_amdgcn_mfma_f32_16x16x32_f16(ak[1], bq[1], acc, 0, 0, 0);
    f32x4 m4 = *(const f32x4*)(mp + fc * 16);
    float p[4];
    tanh_exp4(acc, m4, p);
    f32x4 w4;
    w4[0] = p[0] * rz; w4[1] = p[1] * rz;
    w4[2] = p[2] * rz; w4[3] = p[3] * rz;
    *(f32x4*)(wl + fc * 16) = w4;
  }
}

extern "C" void kernel_launch(void* const* d_in, const int* in_sizes, int n_in,
                              void* d_out, int out_size, void* d_ws, size_t ws_size,
                              hipStream_t stream) {
  const float* Q = (const float*)d_in[0];
  const float* K = (const float*)d_in[1];
  const float* V = (const float*)d_in[2];
  const float* M = (const float*)d_in[3];
  float* Out = (float*)d_out;
  float* W   = Out + (size_t)4 * 16 * 1024 * 64;   // out first, then weights

  const size_t KP_BYTES = 524288, VP_BYTES = 524288, MP_BYTES = 4194304;
  if (ws_size >= KP_BYTES + VP_BYTES + MP_BYTES) {
    f16*   Kp = (f16*)d_ws;
    f16*   Vp = (f16*)((char*)d_ws + KP_BYTES);
    float* Mp = (float*)((char*)d_ws + KP_BYTES + VP_BYTES);
    hipLaunchKernelGGL(prep, dim3(1408), dim3(256), 0, stream, K, V, M, Kp, Vp, Mp);
    hipLaunchKernelGGL(attn_main, dim3(1024), dim3(256), 0, stream,
                       Q, Kp, Vp, Mp, Out, W);
  } else {
    hipLaunchKernelGGL(attn_fused, dim3(1024), dim3(256), 0, stream,
                       Q, K, V, M, Out, W);
  }
}